// Round 1
// baseline (1767.887 us; speedup 1.0000x reference)
//
#include <hip/hip_runtime.h>
#include <hip/hip_bf16.h>

#define B_ 8
#define S_ 1024
#define D_ 512
#define H_ 8
#define DK_ 64
#define HD_ 4096   // H_*D_

static __device__ __forceinline__ float bf2f(unsigned short u) {
    unsigned v = ((unsigned)u) << 16;
    return __uint_as_float(v);
}
static __device__ __forceinline__ unsigned short f2bf(float f) {
    unsigned u = __float_as_uint(f);
    unsigned r = (u + 0x7fffu + ((u >> 16) & 1u)) >> 16;  // round-to-nearest-even
    return (unsigned short)r;
}

// ---------------------------------------------------------------------------
// K1: P = X @ W^T + bias.  X [8192,512] row-major, W [512,512] row-major.
// grid (128, 8), block 256. 64x64 tile, BK=16, 4x4 per thread.
// ---------------------------------------------------------------------------
__global__ __launch_bounds__(256) void proj_kernel(
    const float* __restrict__ X, const float* __restrict__ W,
    const float* __restrict__ bias, float* __restrict__ P)
{
    const int K = D_;
    __shared__ float As[16][68];
    __shared__ float Bs[16][68];
    const int t  = threadIdx.x;
    const int m0 = blockIdx.x * 64;
    const int n0 = blockIdx.y * 64;
    const int lr = t >> 2;          // 0..63
    const int lc = (t & 3) << 2;    // 0,4,8,12
    const int ty = t >> 4;          // 0..15
    const int tx = t & 15;          // 0..15
    float acc[4][4] = {};
    for (int k0 = 0; k0 < K; k0 += 16) {
        float4 a4 = *(const float4*)&X[(size_t)(m0 + lr) * K + k0 + lc];
        As[lc + 0][lr] = a4.x; As[lc + 1][lr] = a4.y;
        As[lc + 2][lr] = a4.z; As[lc + 3][lr] = a4.w;
        float4 b4 = *(const float4*)&W[(size_t)(n0 + lr) * K + k0 + lc];
        Bs[lc + 0][lr] = b4.x; Bs[lc + 1][lr] = b4.y;
        Bs[lc + 2][lr] = b4.z; Bs[lc + 3][lr] = b4.w;
        __syncthreads();
        #pragma unroll
        for (int kk = 0; kk < 16; ++kk) {
            float4 av = *(const float4*)&As[kk][ty * 4];
            float4 bv = *(const float4*)&Bs[kk][tx * 4];
            float a[4] = {av.x, av.y, av.z, av.w};
            float b[4] = {bv.x, bv.y, bv.z, bv.w};
            #pragma unroll
            for (int i = 0; i < 4; ++i)
                #pragma unroll
                for (int j = 0; j < 4; ++j) acc[i][j] += a[i] * b[j];
        }
        __syncthreads();
    }
    #pragma unroll
    for (int i = 0; i < 4; ++i) {
        int m = m0 + ty * 4 + i;
        #pragma unroll
        for (int j = 0; j < 4; ++j) {
            int n = n0 + tx * 4 + j;
            P[(size_t)m * D_ + n] = acc[i][j] + bias[n];
        }
    }
}

// ---------------------------------------------------------------------------
// K2: raw scaled scores per (b,h): Sc[q][k] = 0.125 * Q_h[q,:] . K_h[k,:]
// grid (16,16,64), block 256. Writes f32 into the attn region of d_out.
// ---------------------------------------------------------------------------
__global__ __launch_bounds__(256) void scores_kernel(
    const float* __restrict__ Q, const float* __restrict__ Kp,
    float* __restrict__ attn)
{
    const int bh = blockIdx.z;
    const int b = bh >> 3, h = bh & 7;
    const float* Qb = Q  + (size_t)b * S_ * D_ + h * DK_;
    const float* Kb = Kp + (size_t)b * S_ * D_ + h * DK_;
    float* outp = attn + (size_t)bh * S_ * S_;
    __shared__ float As[16][68];
    __shared__ float Bs[16][68];
    const int t  = threadIdx.x;
    const int m0 = blockIdx.x * 64;   // q
    const int n0 = blockIdx.y * 64;   // k
    const int lr = t >> 2;
    const int lc = (t & 3) << 2;
    const int ty = t >> 4;
    const int tx = t & 15;
    float acc[4][4] = {};
    for (int k0 = 0; k0 < DK_; k0 += 16) {
        float4 a4 = *(const float4*)&Qb[(size_t)(m0 + lr) * D_ + k0 + lc];
        As[lc + 0][lr] = a4.x; As[lc + 1][lr] = a4.y;
        As[lc + 2][lr] = a4.z; As[lc + 3][lr] = a4.w;
        float4 b4 = *(const float4*)&Kb[(size_t)(n0 + lr) * D_ + k0 + lc];
        Bs[lc + 0][lr] = b4.x; Bs[lc + 1][lr] = b4.y;
        Bs[lc + 2][lr] = b4.z; Bs[lc + 3][lr] = b4.w;
        __syncthreads();
        #pragma unroll
        for (int kk = 0; kk < 16; ++kk) {
            float4 av = *(const float4*)&As[kk][ty * 4];
            float4 bv = *(const float4*)&Bs[kk][tx * 4];
            float a[4] = {av.x, av.y, av.z, av.w};
            float b[4] = {bv.x, bv.y, bv.z, bv.w};
            #pragma unroll
            for (int i = 0; i < 4; ++i)
                #pragma unroll
                for (int j = 0; j < 4; ++j) acc[i][j] += a[i] * b[j];
        }
        __syncthreads();
    }
    #pragma unroll
    for (int i = 0; i < 4; ++i) {
        int q = m0 + ty * 4 + i;
        #pragma unroll
        for (int j = 0; j < 4; ++j) {
            int k = n0 + tx * 4 + j;
            outp[(size_t)q * S_ + k] = acc[i][j] * 0.125f;
        }
    }
}

// ---------------------------------------------------------------------------
// K3: per-row (B*H*S rows of 1024) max and 1/sum(exp(x-max)). One wave/row.
// grid 16384, block 256 (4 waves).
// ---------------------------------------------------------------------------
__global__ __launch_bounds__(256) void stats_kernel(
    const float* __restrict__ sc, float* __restrict__ rmax, float* __restrict__ rsum)
{
    const int lane = threadIdx.x & 63;
    const int wave = threadIdx.x >> 6;
    const size_t row = (size_t)blockIdx.x * 4 + wave;
    const float* p = sc + row * S_;
    float4 v[4];
    #pragma unroll
    for (int i = 0; i < 4; ++i) v[i] = *(const float4*)&p[(size_t)(i * 64 + lane) * 4];
    float mx = -3.4e38f;
    #pragma unroll
    for (int i = 0; i < 4; ++i) {
        mx = fmaxf(mx, fmaxf(fmaxf(v[i].x, v[i].y), fmaxf(v[i].z, v[i].w)));
    }
    #pragma unroll
    for (int m = 1; m < 64; m <<= 1) mx = fmaxf(mx, __shfl_xor(mx, m));
    float s = 0.f;
    #pragma unroll
    for (int i = 0; i < 4; ++i) {
        s += __expf(v[i].x - mx) + __expf(v[i].y - mx) +
             __expf(v[i].z - mx) + __expf(v[i].w - mx);
    }
    #pragma unroll
    for (int m = 1; m < 64; m <<= 1) s += __shfl_xor(s, m);
    if (lane == 0) { rmax[row] = mx; rsum[row] = 1.0f / s; }
}

// ---------------------------------------------------------------------------
// K4: attn = exp(s - rowmax) * rinv, in place. grid 65536, block 256, float4.
// ---------------------------------------------------------------------------
__global__ __launch_bounds__(256) void smnorm_kernel(
    float* __restrict__ attn, const float* __restrict__ rmax,
    const float* __restrict__ rsum)
{
    const size_t idx = ((size_t)blockIdx.x * 256 + threadIdx.x) * 4;
    const size_t row = idx >> 10;
    const float mx = rmax[row];
    const float ri = rsum[row];
    float4 v = *(float4*)&attn[idx];
    v.x = __expf(v.x - mx) * ri;
    v.y = __expf(v.y - mx) * ri;
    v.z = __expf(v.z - mx) * ri;
    v.w = __expf(v.w - mx) * ri;
    *(float4*)&attn[idx] = v;
}

// ---------------------------------------------------------------------------
// K5: AV[b, q, h*512 + e] = sum_k attn[b,h,q,k] * V[b,k,e], stored bf16.
// Per (b,h): GEMM [1024x1024]@[1024x512]. grid (16, 8, 64), block 256.
// ---------------------------------------------------------------------------
__global__ __launch_bounds__(256) void av_kernel(
    const float* __restrict__ attn, const float* __restrict__ V,
    unsigned short* __restrict__ AV)
{
    const int bh = blockIdx.z;
    const int b = bh >> 3, h = bh & 7;
    const float* A  = attn + (size_t)bh * S_ * S_;
    const float* Vb = V + (size_t)b * S_ * D_;
    __shared__ float As[16][68];
    __shared__ float Bs[16][68];
    const int t  = threadIdx.x;
    const int m0 = blockIdx.x * 64;   // q
    const int n0 = blockIdx.y * 64;   // e
    const int lr = t >> 2;
    const int lc = (t & 3) << 2;
    const int ty = t >> 4;
    const int tx = t & 15;
    float acc[4][4] = {};
    for (int k0 = 0; k0 < S_; k0 += 16) {
        float4 a4 = *(const float4*)&A[(size_t)(m0 + lr) * S_ + k0 + lc];
        As[lc + 0][lr] = a4.x; As[lc + 1][lr] = a4.y;
        As[lc + 2][lr] = a4.z; As[lc + 3][lr] = a4.w;
        // B tile: Bs[kk][n] = Vb[(k0+kk)*512 + n0+n], coalesced
        {
            int kk = t >> 4;            // 0..15
            int nn = (t & 15) * 4;      // 0..60
            float4 b4 = *(const float4*)&Vb[(size_t)(k0 + kk) * D_ + n0 + nn];
            *(float4*)&Bs[kk][nn] = b4;
        }
        __syncthreads();
        #pragma unroll
        for (int kk = 0; kk < 16; ++kk) {
            float4 av = *(const float4*)&As[kk][ty * 4];
            float4 bv = *(const float4*)&Bs[kk][tx * 4];
            float a[4] = {av.x, av.y, av.z, av.w};
            float b[4] = {bv.x, bv.y, bv.z, bv.w};
            #pragma unroll
            for (int i = 0; i < 4; ++i)
                #pragma unroll
                for (int j = 0; j < 4; ++j) acc[i][j] += a[i] * b[j];
        }
        __syncthreads();
    }
    #pragma unroll
    for (int i = 0; i < 4; ++i) {
        int q = m0 + ty * 4 + i;
        #pragma unroll
        for (int j = 0; j < 4; ++j) {
            int e = n0 + tx * 4 + j;
            AV[((size_t)(b * S_ + q)) * HD_ + h * D_ + e] = f2bf(acc[i][j]);
        }
    }
}

// ---------------------------------------------------------------------------
// K6: y = AV(bf16)[8192x4096] @ Wo^T[512x4096] + bo + value. grid (128,8).
// ---------------------------------------------------------------------------
__global__ __launch_bounds__(256) void out_kernel(
    const unsigned short* __restrict__ AV, const float* __restrict__ Wo,
    const float* __restrict__ bo, const float* __restrict__ Vres,
    float* __restrict__ Y)
{
    __shared__ float As[16][68];
    __shared__ float Bs[16][68];
    const int t  = threadIdx.x;
    const int m0 = blockIdx.x * 64;
    const int n0 = blockIdx.y * 64;
    const int lr = t >> 2;
    const int lc = (t & 3) << 2;
    const int ty = t >> 4;
    const int tx = t & 15;
    float acc[4][4] = {};
    for (int k0 = 0; k0 < HD_; k0 += 16) {
        ushort4 a4 = *(const ushort4*)&AV[(size_t)(m0 + lr) * HD_ + k0 + lc];
        As[lc + 0][lr] = bf2f(a4.x); As[lc + 1][lr] = bf2f(a4.y);
        As[lc + 2][lr] = bf2f(a4.z); As[lc + 3][lr] = bf2f(a4.w);
        float4 b4 = *(const float4*)&Wo[(size_t)(n0 + lr) * HD_ + k0 + lc];
        Bs[lc + 0][lr] = b4.x; Bs[lc + 1][lr] = b4.y;
        Bs[lc + 2][lr] = b4.z; Bs[lc + 3][lr] = b4.w;
        __syncthreads();
        #pragma unroll
        for (int kk = 0; kk < 16; ++kk) {
            float4 av = *(const float4*)&As[kk][ty * 4];
            float4 bv = *(const float4*)&Bs[kk][tx * 4];
            float a[4] = {av.x, av.y, av.z, av.w};
            float b[4] = {bv.x, bv.y, bv.z, bv.w};
            #pragma unroll
            for (int i = 0; i < 4; ++i)
                #pragma unroll
                for (int j = 0; j < 4; ++j) acc[i][j] += a[i] * b[j];
        }
        __syncthreads();
    }
    #pragma unroll
    for (int i = 0; i < 4; ++i) {
        int m = m0 + ty * 4 + i;
        #pragma unroll
        for (int j = 0; j < 4; ++j) {
            int n = n0 + tx * 4 + j;
            size_t o = (size_t)m * D_ + n;
            Y[o] = acc[i][j] + bo[n] + Vres[o];
        }
    }
}

// ---------------------------------------------------------------------------
// K7: LayerNorm in place over rows of 512. One wave per row. grid 2048.
// ---------------------------------------------------------------------------
__global__ __launch_bounds__(256) void ln_kernel(
    float* __restrict__ Y, const float* __restrict__ gamma,
    const float* __restrict__ beta)
{
    const int lane = threadIdx.x & 63;
    const int wave = threadIdx.x >> 6;
    const size_t row = (size_t)blockIdx.x * 4 + wave;
    float* p = Y + row * D_;
    float4 v0 = *(float4*)&p[lane * 4];
    float4 v1 = *(float4*)&p[256 + lane * 4];
    float s = v0.x + v0.y + v0.z + v0.w + v1.x + v1.y + v1.z + v1.w;
    float q = v0.x * v0.x + v0.y * v0.y + v0.z * v0.z + v0.w * v0.w +
              v1.x * v1.x + v1.y * v1.y + v1.z * v1.z + v1.w * v1.w;
    #pragma unroll
    for (int m = 1; m < 64; m <<= 1) {
        s += __shfl_xor(s, m);
        q += __shfl_xor(q, m);
    }
    const float mu  = s * (1.f / 512.f);
    const float var = q * (1.f / 512.f) - mu * mu;
    const float r = rsqrtf(var + 1e-5f);
    const float4 g0 = *(const float4*)&gamma[lane * 4];
    const float4 g1 = *(const float4*)&gamma[256 + lane * 4];
    const float4 b0 = *(const float4*)&beta[lane * 4];
    const float4 b1 = *(const float4*)&beta[256 + lane * 4];
    v0.x = (v0.x - mu) * r * g0.x + b0.x;
    v0.y = (v0.y - mu) * r * g0.y + b0.y;
    v0.z = (v0.z - mu) * r * g0.z + b0.z;
    v0.w = (v0.w - mu) * r * g0.w + b0.w;
    v1.x = (v1.x - mu) * r * g1.x + b1.x;
    v1.y = (v1.y - mu) * r * g1.y + b1.y;
    v1.z = (v1.z - mu) * r * g1.z + b1.z;
    v1.w = (v1.w - mu) * r * g1.w + b1.w;
    *(float4*)&p[lane * 4] = v0;
    *(float4*)&p[256 + lane * 4] = v1;
}

// ---------------------------------------------------------------------------
extern "C" void kernel_launch(void* const* d_in, const int* in_sizes, int n_in,
                              void* d_out, int out_size, void* d_ws, size_t ws_size,
                              hipStream_t stream)
{
    const float* query = (const float*)d_in[0];
    const float* key   = (const float*)d_in[1];
    const float* value = (const float*)d_in[2];
    const float* Wq    = (const float*)d_in[3];
    const float* bq    = (const float*)d_in[4];
    const float* Wk    = (const float*)d_in[5];
    const float* bk    = (const float*)d_in[6];
    const float* Wo    = (const float*)d_in[7];
    const float* bo    = (const float*)d_in[8];
    const float* gamma = (const float*)d_in[9];
    const float* beta  = (const float*)d_in[10];

    float* out  = (float*)d_out;                       // [B,S,D]
    float* attn = out + (size_t)B_ * S_ * D_;          // [B,H,S,S]

    char* ws = (char*)d_ws;
    // Q,K live at [0, 33.5MB) until scores_kernel completes; AV (64MB at
    // offset 0) is written only afterwards (stream-ordered), so they overlap.
    float* Qf = (float*)ws;                                  // 16 MB
    float* Kf = (float*)(ws + ((size_t)16 << 20));           // 16 MB
    unsigned short* AV = (unsigned short*)ws;                // 64 MB (bf16)
    float* rmax = (float*)(ws + ((size_t)68 << 20));         // 256 KB
    float* rsum = (float*)(ws + ((size_t)69 << 20));         // 256 KB

    proj_kernel<<<dim3(128, 8), 256, 0, stream>>>(query, Wq, bq, Qf);
    proj_kernel<<<dim3(128, 8), 256, 0, stream>>>(key,   Wk, bk, Kf);
    scores_kernel<<<dim3(16, 16, 64), 256, 0, stream>>>(Qf, Kf, attn);
    stats_kernel<<<dim3(16384), 256, 0, stream>>>(attn, rmax, rsum);
    smnorm_kernel<<<dim3(65536), 256, 0, stream>>>(attn, rmax, rsum);
    av_kernel<<<dim3(16, 8, 64), 256, 0, stream>>>(attn, value, AV);
    out_kernel<<<dim3(128, 8), 256, 0, stream>>>(AV, Wo, bo, value, out);
    ln_kernel<<<dim3(2048), 256, 0, stream>>>(out, gamma, beta);
}

// Round 2
// 699.675 us; speedup vs baseline: 2.5267x; 2.5267x over previous
//
#include <hip/hip_runtime.h>
#include <hip/hip_bf16.h>

#define B_ 8
#define S_ 1024
#define D_ 512
#define H_ 8
#define DK_ 64
#define HD_ 4096   // H_*D_

typedef __attribute__((ext_vector_type(8))) short bf16x8;
typedef __attribute__((ext_vector_type(4))) float f32x4;

static __device__ __forceinline__ float bf2f(unsigned short u) {
    unsigned v = ((unsigned)u) << 16;
    return __uint_as_float(v);
}
static __device__ __forceinline__ unsigned short f2bf(float f) {
    unsigned u = __float_as_uint(f);
    unsigned r = (u + 0x7fffu + ((u >> 16) & 1u)) >> 16;  // RNE
    return (unsigned short)r;
}

// ---------------------------------------------------------------------------
// K1: P = X @ W^T + bias (f32 VALU, unchanged). grid (128,8), block 256.
// ---------------------------------------------------------------------------
__global__ __launch_bounds__(256) void proj_kernel(
    const float* __restrict__ X, const float* __restrict__ W,
    const float* __restrict__ bias, float* __restrict__ P)
{
    const int K = D_;
    __shared__ float As[16][68];
    __shared__ float Bs[16][68];
    const int t  = threadIdx.x;
    const int m0 = blockIdx.x * 64;
    const int n0 = blockIdx.y * 64;
    const int lr = t >> 2;
    const int lc = (t & 3) << 2;
    const int ty = t >> 4;
    const int tx = t & 15;
    float acc[4][4] = {};
    for (int k0 = 0; k0 < K; k0 += 16) {
        float4 a4 = *(const float4*)&X[(size_t)(m0 + lr) * K + k0 + lc];
        As[lc + 0][lr] = a4.x; As[lc + 1][lr] = a4.y;
        As[lc + 2][lr] = a4.z; As[lc + 3][lr] = a4.w;
        float4 b4 = *(const float4*)&W[(size_t)(n0 + lr) * K + k0 + lc];
        Bs[lc + 0][lr] = b4.x; Bs[lc + 1][lr] = b4.y;
        Bs[lc + 2][lr] = b4.z; Bs[lc + 3][lr] = b4.w;
        __syncthreads();
        #pragma unroll
        for (int kk = 0; kk < 16; ++kk) {
            float4 av = *(const float4*)&As[kk][ty * 4];
            float4 bv = *(const float4*)&Bs[kk][tx * 4];
            float a[4] = {av.x, av.y, av.z, av.w};
            float b[4] = {bv.x, bv.y, bv.z, bv.w};
            #pragma unroll
            for (int i = 0; i < 4; ++i)
                #pragma unroll
                for (int j = 0; j < 4; ++j) acc[i][j] += a[i] * b[j];
        }
        __syncthreads();
    }
    #pragma unroll
    for (int i = 0; i < 4; ++i) {
        int m = m0 + ty * 4 + i;
        #pragma unroll
        for (int j = 0; j < 4; ++j) {
            int n = n0 + tx * 4 + j;
            P[(size_t)m * D_ + n] = acc[i][j] + bias[n];
        }
    }
}

// ---------------------------------------------------------------------------
// K2: raw scaled scores (f32 VALU, unchanged). grid (16,16,64), block 256.
// ---------------------------------------------------------------------------
__global__ __launch_bounds__(256) void scores_kernel(
    const float* __restrict__ Q, const float* __restrict__ Kp,
    float* __restrict__ attn)
{
    const int bh = blockIdx.z;
    const int b = bh >> 3, h = bh & 7;
    const float* Qb = Q  + (size_t)b * S_ * D_ + h * DK_;
    const float* Kb = Kp + (size_t)b * S_ * D_ + h * DK_;
    float* outp = attn + (size_t)bh * S_ * S_;
    __shared__ float As[16][68];
    __shared__ float Bs[16][68];
    const int t  = threadIdx.x;
    const int m0 = blockIdx.x * 64;
    const int n0 = blockIdx.y * 64;
    const int lr = t >> 2;
    const int lc = (t & 3) << 2;
    const int ty = t >> 4;
    const int tx = t & 15;
    float acc[4][4] = {};
    for (int k0 = 0; k0 < DK_; k0 += 16) {
        float4 a4 = *(const float4*)&Qb[(size_t)(m0 + lr) * D_ + k0 + lc];
        As[lc + 0][lr] = a4.x; As[lc + 1][lr] = a4.y;
        As[lc + 2][lr] = a4.z; As[lc + 3][lr] = a4.w;
        float4 b4 = *(const float4*)&Kb[(size_t)(n0 + lr) * D_ + k0 + lc];
        Bs[lc + 0][lr] = b4.x; Bs[lc + 1][lr] = b4.y;
        Bs[lc + 2][lr] = b4.z; Bs[lc + 3][lr] = b4.w;
        __syncthreads();
        #pragma unroll
        for (int kk = 0; kk < 16; ++kk) {
            float4 av = *(const float4*)&As[kk][ty * 4];
            float4 bv = *(const float4*)&Bs[kk][tx * 4];
            float a[4] = {av.x, av.y, av.z, av.w};
            float b[4] = {bv.x, bv.y, bv.z, bv.w};
            #pragma unroll
            for (int i = 0; i < 4; ++i)
                #pragma unroll
                for (int j = 0; j < 4; ++j) acc[i][j] += a[i] * b[j];
        }
        __syncthreads();
    }
    #pragma unroll
    for (int i = 0; i < 4; ++i) {
        int q = m0 + ty * 4 + i;
        #pragma unroll
        for (int j = 0; j < 4; ++j) {
            int k = n0 + tx * 4 + j;
            outp[(size_t)q * S_ + k] = acc[i][j] * 0.125f;
        }
    }
}

// ---------------------------------------------------------------------------
// K3: fused softmax, one block per row (1024 f32). grid 65536, block 256.
// Reads + writes each row once (saves the separate stats pass).
// ---------------------------------------------------------------------------
__global__ __launch_bounds__(256) void softmax_kernel(float* __restrict__ attn)
{
    const size_t row = blockIdx.x;
    float* p = attn + (row << 10);
    const int t = threadIdx.x, lane = t & 63, wave = t >> 6;
    __shared__ float red[8];
    float4 v = *(float4*)&p[t * 4];
    float m = fmaxf(fmaxf(v.x, v.y), fmaxf(v.z, v.w));
    #pragma unroll
    for (int o = 1; o < 64; o <<= 1) m = fmaxf(m, __shfl_xor(m, o));
    if (lane == 0) red[wave] = m;
    __syncthreads();
    m = fmaxf(fmaxf(red[0], red[1]), fmaxf(red[2], red[3]));
    v.x = __expf(v.x - m); v.y = __expf(v.y - m);
    v.z = __expf(v.z - m); v.w = __expf(v.w - m);
    float s = v.x + v.y + v.z + v.w;
    #pragma unroll
    for (int o = 1; o < 64; o <<= 1) s += __shfl_xor(s, o);
    if (lane == 0) red[4 + wave] = s;
    __syncthreads();
    s = red[4] + red[5] + red[6] + red[7];
    const float ri = 1.0f / s;
    v.x *= ri; v.y *= ri; v.z *= ri; v.w *= ri;
    *(float4*)&p[t * 4] = v;
}

// ---------------------------------------------------------------------------
// K4: V transpose+convert: Vt[b][e][s] bf16 from V[b][s][e] f32.
// grid (32, 16, 8), block 256. 32x32 tiles via LDS.
// ---------------------------------------------------------------------------
__global__ __launch_bounds__(256) void vt_kernel(
    const float* __restrict__ V, unsigned short* __restrict__ Vt)
{
    __shared__ float tile[32][33];
    const int b = blockIdx.z, s0 = blockIdx.x * 32, e0 = blockIdx.y * 32;
    const int t = threadIdx.x;
    const int r = t >> 3, c4 = (t & 7) * 4;
    float4 v = *(const float4*)&V[((size_t)b * S_ + s0 + r) * D_ + e0 + c4];
    tile[r][c4 + 0] = v.x; tile[r][c4 + 1] = v.y;
    tile[r][c4 + 2] = v.z; tile[r][c4 + 3] = v.w;
    __syncthreads();
    ushort4 u;
    u.x = f2bf(tile[c4 + 0][r]); u.y = f2bf(tile[c4 + 1][r]);
    u.z = f2bf(tile[c4 + 2][r]); u.w = f2bf(tile[c4 + 3][r]);
    *(ushort4*)&Vt[((size_t)b * D_ + e0 + r) * S_ + s0 + c4] = u;
}

// ---------------------------------------------------------------------------
// K5: Wo f32 -> bf16. grid 2048, block 256.
// ---------------------------------------------------------------------------
__global__ __launch_bounds__(256) void wobf_kernel(
    const float* __restrict__ Wo, unsigned short* __restrict__ Wobf)
{
    const size_t i = ((size_t)blockIdx.x * 256 + threadIdx.x) * 4;
    float4 v = *(const float4*)&Wo[i];
    ushort4 u = { f2bf(v.x), f2bf(v.y), f2bf(v.z), f2bf(v.w) };
    *(ushort4*)&Wobf[i] = u;
}

// ---------------------------------------------------------------------------
// K6: AV = P @ V per (b,h), MFMA bf16. Tile M=64 x N=512, BK=32.
// grid (16, 64), block 256 (4 waves; wave w owns cols w*128..w*128+127).
// A (attn f32) reg-staged with cvt; B from Vt bf16 (k-contiguous rows).
// LDS row stride 40 bf16 (80 B): 16B-aligned b128, conflict-free frag reads.
// ---------------------------------------------------------------------------
__global__ __launch_bounds__(256) void av_mfma(
    const float* __restrict__ attn, const unsigned short* __restrict__ Vt,
    unsigned short* __restrict__ AV)
{
    const int bh = blockIdx.y;
    const int b = bh >> 3, h = bh & 7;
    const float* A = attn + (size_t)bh * S_ * S_;
    const unsigned short* Bt = Vt + (size_t)b * D_ * S_;   // [512][1024]
    const int q0 = blockIdx.x * 64;

    __shared__ unsigned short As[64][40];
    __shared__ unsigned short Bs[512][40];

    const int t = threadIdx.x;
    const int wave = t >> 6, lane = t & 63;
    const int wc = wave * 128;
    const int lr = lane & 15;
    const int lk = (lane >> 4) * 8;
    const int srow = t >> 2;      // 0..63
    const int skc  = t & 3;       // 0..3 (k-chunk of 8)

    f32x4 acc[4][8];
    #pragma unroll
    for (int r = 0; r < 4; ++r)
        #pragma unroll
        for (int c = 0; c < 8; ++c) acc[r][c] = (f32x4){0.f, 0.f, 0.f, 0.f};

    for (int k0 = 0; k0 < S_; k0 += 32) {
        // A stage: 64x32 f32 -> bf16
        {
            const float* src = A + (size_t)(q0 + srow) * S_ + k0 + skc * 8;
            float4 x = *(const float4*)src;
            float4 y = *(const float4*)(src + 4);
            unsigned short tmp[8] = { f2bf(x.x), f2bf(x.y), f2bf(x.z), f2bf(x.w),
                                      f2bf(y.x), f2bf(y.y), f2bf(y.z), f2bf(y.w) };
            *(uint4*)&As[srow][skc * 8] = *(uint4*)tmp;
        }
        // B stage: 512 cols x 32 k bf16 from Vt rows (contiguous)
        #pragma unroll
        for (int g = 0; g < 8; ++g) {
            const int col = srow + g * 64;
            uint4 u = *(const uint4*)(Bt + (size_t)col * S_ + k0 + skc * 8);
            *(uint4*)&Bs[col][skc * 8] = u;
        }
        __syncthreads();
        bf16x8 af[4];
        #pragma unroll
        for (int r = 0; r < 4; ++r)
            af[r] = *(const bf16x8*)&As[r * 16 + lr][lk];
        #pragma unroll
        for (int c = 0; c < 8; ++c) {
            bf16x8 bf = *(const bf16x8*)&Bs[wc + c * 16 + lr][lk];
            #pragma unroll
            for (int r = 0; r < 4; ++r)
                acc[r][c] = __builtin_amdgcn_mfma_f32_16x16x32_bf16(af[r], bf, acc[r][c], 0, 0, 0);
        }
        __syncthreads();
    }
    // write AV[b, q, h*512 + col] bf16
    #pragma unroll
    for (int r = 0; r < 4; ++r) {
        #pragma unroll
        for (int c = 0; c < 8; ++c) {
            const int col = wc + c * 16 + lr;
            #pragma unroll
            for (int i = 0; i < 4; ++i) {
                const int row = q0 + r * 16 + (lane >> 4) * 4 + i;
                AV[((size_t)(b * S_ + row)) * HD_ + h * D_ + col] = f2bf(acc[r][c][i]);
            }
        }
    }
}

// ---------------------------------------------------------------------------
// K7: Y = AV(bf16) @ Wobf^T + bo + value, MFMA. Tile M=64 x N=256, BK=32.
// grid (128, 2), block 256 (4 waves; wave w owns cols w*64..w*64+63).
// ---------------------------------------------------------------------------
__global__ __launch_bounds__(256) void out_mfma(
    const unsigned short* __restrict__ AV, const unsigned short* __restrict__ Wobf,
    const float* __restrict__ bo, const float* __restrict__ Vres,
    float* __restrict__ Y)
{
    const int m0 = blockIdx.x * 64;
    const int n0 = blockIdx.y * 256;

    __shared__ unsigned short As[64][40];
    __shared__ unsigned short Bs[256][40];

    const int t = threadIdx.x;
    const int wave = t >> 6, lane = t & 63;
    const int wc = wave * 64;
    const int lr = lane & 15;
    const int lk = (lane >> 4) * 8;
    const int srow = t >> 2;
    const int skc  = t & 3;

    f32x4 acc[4][4];
    #pragma unroll
    for (int r = 0; r < 4; ++r)
        #pragma unroll
        for (int c = 0; c < 4; ++c) acc[r][c] = (f32x4){0.f, 0.f, 0.f, 0.f};

    for (int k0 = 0; k0 < HD_; k0 += 32) {
        {
            uint4 u = *(const uint4*)(AV + (size_t)(m0 + srow) * HD_ + k0 + skc * 8);
            *(uint4*)&As[srow][skc * 8] = u;
        }
        #pragma unroll
        for (int g = 0; g < 4; ++g) {
            const int col = srow + g * 64;
            uint4 u = *(const uint4*)(Wobf + (size_t)(n0 + col) * HD_ + k0 + skc * 8);
            *(uint4*)&Bs[col][skc * 8] = u;
        }
        __syncthreads();
        bf16x8 af[4];
        #pragma unroll
        for (int r = 0; r < 4; ++r)
            af[r] = *(const bf16x8*)&As[r * 16 + lr][lk];
        #pragma unroll
        for (int c = 0; c < 4; ++c) {
            bf16x8 bf = *(const bf16x8*)&Bs[wc + c * 16 + lr][lk];
            #pragma unroll
            for (int r = 0; r < 4; ++r)
                acc[r][c] = __builtin_amdgcn_mfma_f32_16x16x32_bf16(af[r], bf, acc[r][c], 0, 0, 0);
        }
        __syncthreads();
    }
    #pragma unroll
    for (int r = 0; r < 4; ++r) {
        #pragma unroll
        for (int c = 0; c < 4; ++c) {
            const int n = n0 + wc + c * 16 + lr;
            #pragma unroll
            for (int i = 0; i < 4; ++i) {
                const int m = m0 + r * 16 + (lane >> 4) * 4 + i;
                const size_t o = (size_t)m * D_ + n;
                Y[o] = acc[r][c][i] + bo[n] + Vres[o];
            }
        }
    }
}

// ---------------------------------------------------------------------------
// K8: LayerNorm in place (unchanged). grid 2048, block 256.
// ---------------------------------------------------------------------------
__global__ __launch_bounds__(256) void ln_kernel(
    float* __restrict__ Y, const float* __restrict__ gamma,
    const float* __restrict__ beta)
{
    const int lane = threadIdx.x & 63;
    const int wave = threadIdx.x >> 6;
    const size_t row = (size_t)blockIdx.x * 4 + wave;
    float* p = Y + row * D_;
    float4 v0 = *(float4*)&p[lane * 4];
    float4 v1 = *(float4*)&p[256 + lane * 4];
    float s = v0.x + v0.y + v0.z + v0.w + v1.x + v1.y + v1.z + v1.w;
    float q = v0.x * v0.x + v0.y * v0.y + v0.z * v0.z + v0.w * v0.w +
              v1.x * v1.x + v1.y * v1.y + v1.z * v1.z + v1.w * v1.w;
    #pragma unroll
    for (int m = 1; m < 64; m <<= 1) {
        s += __shfl_xor(s, m);
        q += __shfl_xor(q, m);
    }
    const float mu  = s * (1.f / 512.f);
    const float var = q * (1.f / 512.f) - mu * mu;
    const float r = rsqrtf(var + 1e-5f);
    const float4 g0 = *(const float4*)&gamma[lane * 4];
    const float4 g1 = *(const float4*)&gamma[256 + lane * 4];
    const float4 b0 = *(const float4*)&beta[lane * 4];
    const float4 b1 = *(const float4*)&beta[256 + lane * 4];
    v0.x = (v0.x - mu) * r * g0.x + b0.x;
    v0.y = (v0.y - mu) * r * g0.y + b0.y;
    v0.z = (v0.z - mu) * r * g0.z + b0.z;
    v0.w = (v0.w - mu) * r * g0.w + b0.w;
    v1.x = (v1.x - mu) * r * g1.x + b1.x;
    v1.y = (v1.y - mu) * r * g1.y + b1.y;
    v1.z = (v1.z - mu) * r * g1.z + b1.z;
    v1.w = (v1.w - mu) * r * g1.w + b1.w;
    *(float4*)&p[lane * 4] = v0;
    *(float4*)&p[256 + lane * 4] = v1;
}

// ---------------------------------------------------------------------------
extern "C" void kernel_launch(void* const* d_in, const int* in_sizes, int n_in,
                              void* d_out, int out_size, void* d_ws, size_t ws_size,
                              hipStream_t stream)
{
    const float* query = (const float*)d_in[0];
    const float* key   = (const float*)d_in[1];
    const float* value = (const float*)d_in[2];
    const float* Wq    = (const float*)d_in[3];
    const float* bq    = (const float*)d_in[4];
    const float* Wk    = (const float*)d_in[5];
    const float* bk    = (const float*)d_in[6];
    const float* Wo    = (const float*)d_in[7];
    const float* bo    = (const float*)d_in[8];
    const float* gamma = (const float*)d_in[9];
    const float* beta  = (const float*)d_in[10];

    float* out  = (float*)d_out;                       // [B,S,D]
    float* attn = out + (size_t)B_ * S_ * D_;          // [B,H,S,S]

    char* ws = (char*)d_ws;
    // Layout (76 MB):
    //   [0,64)   AV bf16 [8192][4096]  (written after Qf/Kf are dead)
    //   [0,16)   Qf f32   (dead after scores)
    //   [16,32)  Kf f32   (dead after scores)
    //   [64,72)  Vt bf16  [8][512][1024]
    //   [72,76)  Wobf bf16 [512][4096]
    unsigned short* AV   = (unsigned short*)ws;
    float* Qf            = (float*)ws;
    float* Kf            = (float*)(ws + ((size_t)16 << 20));
    unsigned short* Vt   = (unsigned short*)(ws + ((size_t)64 << 20));
    unsigned short* Wobf = (unsigned short*)(ws + ((size_t)72 << 20));

    vt_kernel<<<dim3(32, 16, 8), 256, 0, stream>>>(value, Vt);
    wobf_kernel<<<dim3(2048), 256, 0, stream>>>(Wo, Wobf);
    proj_kernel<<<dim3(128, 8), 256, 0, stream>>>(query, Wq, bq, Qf);
    proj_kernel<<<dim3(128, 8), 256, 0, stream>>>(key,   Wk, bk, Kf);
    scores_kernel<<<dim3(16, 16, 64), 256, 0, stream>>>(Qf, Kf, attn);
    softmax_kernel<<<dim3(65536), 256, 0, stream>>>(attn);
    av_mfma<<<dim3(16, 64), 256, 0, stream>>>(attn, Vt, AV);
    out_mfma<<<dim3(128, 2), 256, 0, stream>>>(AV, Wobf, bo, value, out);
    ln_kernel<<<dim3(2048), 256, 0, stream>>>(out, gamma, beta);
}

// Round 3
// 642.913 us; speedup vs baseline: 2.7498x; 1.0883x over previous
//
#include <hip/hip_runtime.h>
#include <hip/hip_bf16.h>

#define B_ 8
#define S_ 1024
#define D_ 512
#define H_ 8
#define DK_ 64
#define HD_ 4096   // H_*D_

typedef __attribute__((ext_vector_type(8))) short bf16x8;
typedef __attribute__((ext_vector_type(4))) float f32x4;

static __device__ __forceinline__ float bf2f(unsigned short u) {
    unsigned v = ((unsigned)u) << 16;
    return __uint_as_float(v);
}
static __device__ __forceinline__ unsigned short f2bf(float f) {
    unsigned u = __float_as_uint(f);
    unsigned r = (u + 0x7fffu + ((u >> 16) & 1u)) >> 16;  // RNE
    return (unsigned short)r;
}

// ---------------------------------------------------------------------------
// K1: P = X @ W^T + bias (f32 VALU), output bf16 at [B][H][S][dk] layout.
// grid (128,8), block 256.
// ---------------------------------------------------------------------------
__global__ __launch_bounds__(256) void proj_kernel(
    const float* __restrict__ X, const float* __restrict__ W,
    const float* __restrict__ bias, unsigned short* __restrict__ P)
{
    const int K = D_;
    __shared__ float As[16][68];
    __shared__ float Bs[16][68];
    const int t  = threadIdx.x;
    const int m0 = blockIdx.x * 64;
    const int n0 = blockIdx.y * 64;
    const int lr = t >> 2;
    const int lc = (t & 3) << 2;
    const int ty = t >> 4;
    const int tx = t & 15;
    float acc[4][4] = {};
    for (int k0 = 0; k0 < K; k0 += 16) {
        float4 a4 = *(const float4*)&X[(size_t)(m0 + lr) * K + k0 + lc];
        As[lc + 0][lr] = a4.x; As[lc + 1][lr] = a4.y;
        As[lc + 2][lr] = a4.z; As[lc + 3][lr] = a4.w;
        float4 b4 = *(const float4*)&W[(size_t)(n0 + lr) * K + k0 + lc];
        Bs[lc + 0][lr] = b4.x; Bs[lc + 1][lr] = b4.y;
        Bs[lc + 2][lr] = b4.z; Bs[lc + 3][lr] = b4.w;
        __syncthreads();
        #pragma unroll
        for (int kk = 0; kk < 16; ++kk) {
            float4 av = *(const float4*)&As[kk][ty * 4];
            float4 bv = *(const float4*)&Bs[kk][tx * 4];
            float a[4] = {av.x, av.y, av.z, av.w};
            float b[4] = {bv.x, bv.y, bv.z, bv.w};
            #pragma unroll
            for (int i = 0; i < 4; ++i)
                #pragma unroll
                for (int j = 0; j < 4; ++j) acc[i][j] += a[i] * b[j];
        }
        __syncthreads();
    }
    // write bf16 at [b][h][s][dk]: m = b*1024+s ; n = h*64+dk
    const int b = (m0 + 0) >> 10;           // 64-row tile never crosses b
    #pragma unroll
    for (int i = 0; i < 4; ++i) {
        int m = m0 + ty * 4 + i;
        int s = m & 1023;
        #pragma unroll
        for (int j = 0; j < 4; ++j) {
            int n = n0 + tx * 4 + j;
            int h = n >> 6, dk = n & 63;
            P[((((size_t)b * H_ + h) * S_) + s) * DK_ + dk] = f2bf(acc[i][j] + bias[n]);
        }
    }
}

// ---------------------------------------------------------------------------
// K2: V transpose+convert: Vt[b][e][s] bf16 from V[b][s][e] f32.
// ---------------------------------------------------------------------------
__global__ __launch_bounds__(256) void vt_kernel(
    const float* __restrict__ V, unsigned short* __restrict__ Vt)
{
    __shared__ float tile[32][33];
    const int b = blockIdx.z, s0 = blockIdx.x * 32, e0 = blockIdx.y * 32;
    const int t = threadIdx.x;
    const int r = t >> 3, c4 = (t & 7) * 4;
    float4 v = *(const float4*)&V[((size_t)b * S_ + s0 + r) * D_ + e0 + c4];
    tile[r][c4 + 0] = v.x; tile[r][c4 + 1] = v.y;
    tile[r][c4 + 2] = v.z; tile[r][c4 + 3] = v.w;
    __syncthreads();
    ushort4 u;
    u.x = f2bf(tile[c4 + 0][r]); u.y = f2bf(tile[c4 + 1][r]);
    u.z = f2bf(tile[c4 + 2][r]); u.w = f2bf(tile[c4 + 3][r]);
    *(ushort4*)&Vt[((size_t)b * D_ + e0 + r) * S_ + s0 + c4] = u;
}

// ---------------------------------------------------------------------------
// K3: Wo f32 -> bf16.
// ---------------------------------------------------------------------------
__global__ __launch_bounds__(256) void wobf_kernel(
    const float* __restrict__ Wo, unsigned short* __restrict__ Wobf)
{
    const size_t i = ((size_t)blockIdx.x * 256 + threadIdx.x) * 4;
    float4 v = *(const float4*)&Wo[i];
    ushort4 u = { f2bf(v.x), f2bf(v.y), f2bf(v.z), f2bf(v.w) };
    *(ushort4*)&Wobf[i] = u;
}

// ---------------------------------------------------------------------------
// K4: fused scores + softmax. One block per (b,h,q-tile of 64). 8 waves.
// Wave w owns k-cols [w*128, w*128+128). Whole S-tile lives in acc regs.
// Writes normalized attn f32 once.
// ---------------------------------------------------------------------------
__global__ __launch_bounds__(512, 2) void qk_softmax(
    const unsigned short* __restrict__ Qbf, const unsigned short* __restrict__ Kbf,
    float* __restrict__ attn)
{
    const int bh = blockIdx.y;
    const int q0 = blockIdx.x * 64;
    const unsigned short* Qb = Qbf + (size_t)bh * S_ * DK_;
    const unsigned short* Kb = Kbf + (size_t)bh * S_ * DK_;
    float* outp = attn + ((size_t)bh << 20);

    __shared__ unsigned short Qs[64 * 64];  // rows of 128B, slot-XOR swizzled
    __shared__ float redm[64][8];
    __shared__ float rowm[64];

    const int t = threadIdx.x;
    const int wave = t >> 6, lane = t & 63;
    const int wcol = wave * 128;
    const int lr = lane & 15;
    const int g  = lane >> 4;          // 0..3

    // stage Q tile: thread t covers 16B slot s of row r (swizzled)
    {
        const int r = t >> 3, s = t & 7;
        uint4 u = *(const uint4*)&Qb[(size_t)(q0 + r) * DK_ + s * 8];
        *(uint4*)&Qs[r * 64 + ((s ^ (r & 7)) * 8)] = u;
    }
    __syncthreads();

    f32x4 acc[4][8];
    #pragma unroll
    for (int r = 0; r < 4; ++r)
        #pragma unroll
        for (int c = 0; c < 8; ++c) acc[r][c] = (f32x4){0.f, 0.f, 0.f, 0.f};

    #pragma unroll
    for (int kk = 0; kk < 2; ++kk) {
        bf16x8 af[4];
        #pragma unroll
        for (int r = 0; r < 4; ++r) {
            const int row = r * 16 + lr;
            const int slot = kk * 4 + g;
            af[r] = *(const bf16x8*)&Qs[row * 64 + ((slot ^ (row & 7)) * 8)];
        }
        #pragma unroll
        for (int c = 0; c < 8; ++c) {
            const int col = wcol + c * 16 + lr;
            bf16x8 bf = *(const bf16x8*)&Kb[(size_t)col * DK_ + kk * 32 + g * 8];
            #pragma unroll
            for (int r = 0; r < 4; ++r)
                acc[r][c] = __builtin_amdgcn_mfma_f32_16x16x32_bf16(af[r], bf, acc[r][c], 0, 0, 0);
        }
    }

    // scale
    #pragma unroll
    for (int r = 0; r < 4; ++r)
        #pragma unroll
        for (int c = 0; c < 8; ++c)
            #pragma unroll
            for (int i = 0; i < 4; ++i) acc[r][c][i] *= 0.125f;

    // wave-local row max (over this wave's 128 cols)
    float mri[4][4];
    #pragma unroll
    for (int r = 0; r < 4; ++r)
        #pragma unroll
        for (int i = 0; i < 4; ++i) {
            float m = acc[r][0][i];
            #pragma unroll
            for (int c = 1; c < 8; ++c) m = fmaxf(m, acc[r][c][i]);
            #pragma unroll
            for (int o = 1; o < 16; o <<= 1) m = fmaxf(m, __shfl_xor(m, o));
            mri[r][i] = m;
        }
    if (lr == 0) {
        #pragma unroll
        for (int r = 0; r < 4; ++r)
            #pragma unroll
            for (int i = 0; i < 4; ++i) redm[r * 16 + g * 4 + i][wave] = mri[r][i];
    }
    __syncthreads();
    if (t < 64) {
        float m = redm[t][0];
        #pragma unroll
        for (int w = 1; w < 8; ++w) m = fmaxf(m, redm[t][w]);
        rowm[t] = m;
    }
    __syncthreads();
    // p = exp(s - m), accumulate row sums
    float sri[4][4];
    #pragma unroll
    for (int r = 0; r < 4; ++r)
        #pragma unroll
        for (int i = 0; i < 4; ++i) {
            const float m = rowm[r * 16 + g * 4 + i];
            float s = 0.f;
            #pragma unroll
            for (int c = 0; c < 8; ++c) {
                float p = __expf(acc[r][c][i] - m);
                acc[r][c][i] = p;
                s += p;
            }
            #pragma unroll
            for (int o = 1; o < 16; o <<= 1) s += __shfl_xor(s, o);
            sri[r][i] = s;
        }
    __syncthreads();   // redm reuse hazard
    if (lr == 0) {
        #pragma unroll
        for (int r = 0; r < 4; ++r)
            #pragma unroll
            for (int i = 0; i < 4; ++i) redm[r * 16 + g * 4 + i][wave] = sri[r][i];
    }
    __syncthreads();
    if (t < 64) {
        float s = redm[t][0];
        #pragma unroll
        for (int w = 1; w < 8; ++w) s += redm[t][w];
        rowm[t] = 1.0f / s;
    }
    __syncthreads();
    #pragma unroll
    for (int r = 0; r < 4; ++r)
        #pragma unroll
        for (int i = 0; i < 4; ++i) {
            const float ri = rowm[r * 16 + g * 4 + i];
            const size_t rowoff = (size_t)(q0 + r * 16 + g * 4 + i) << 10;
            #pragma unroll
            for (int c = 0; c < 8; ++c)
                outp[rowoff + wcol + c * 16 + lr] = acc[r][c][i] * ri;
        }
}

// ---------------------------------------------------------------------------
// K5: AV = attn @ V per (b,h). No LDS, no barriers: fragments direct from
// global (attn f32 inline-cvt; Vt bf16). grid (16, 64), block 256 (4 waves);
// wave w owns e-cols [w*128, w*128+128).
// ---------------------------------------------------------------------------
__global__ __launch_bounds__(256) void av_frag(
    const float* __restrict__ attn, const unsigned short* __restrict__ Vt,
    unsigned short* __restrict__ AV)
{
    const int bh = blockIdx.y;
    const int b = bh >> 3, h = bh & 7;
    const float* A = attn + ((size_t)bh << 20);
    const unsigned short* Bt = Vt + (size_t)b * D_ * S_;
    const int q0 = blockIdx.x * 64;

    const int t = threadIdx.x;
    const int wave = t >> 6, lane = t & 63;
    const int wc = wave * 128;
    const int lr = lane & 15;
    const int lk = (lane >> 4) * 8;

    f32x4 acc[4][8];
    #pragma unroll
    for (int r = 0; r < 4; ++r)
        #pragma unroll
        for (int c = 0; c < 8; ++c) acc[r][c] = (f32x4){0.f, 0.f, 0.f, 0.f};

    for (int k0 = 0; k0 < S_; k0 += 32) {
        bf16x8 af[4];
        #pragma unroll
        for (int r = 0; r < 4; ++r) {
            const float* ap = A + ((size_t)(q0 + r * 16 + lr) << 10) + k0 + lk;
            float4 x = *(const float4*)ap;
            float4 y = *(const float4*)(ap + 4);
            unsigned short tmp[8] = { f2bf(x.x), f2bf(x.y), f2bf(x.z), f2bf(x.w),
                                      f2bf(y.x), f2bf(y.y), f2bf(y.z), f2bf(y.w) };
            af[r] = *(const bf16x8*)tmp;
        }
        #pragma unroll
        for (int c = 0; c < 8; ++c) {
            bf16x8 bf = *(const bf16x8*)&Bt[(size_t)(wc + c * 16 + lr) * S_ + k0 + lk];
            #pragma unroll
            for (int r = 0; r < 4; ++r)
                acc[r][c] = __builtin_amdgcn_mfma_f32_16x16x32_bf16(af[r], bf, acc[r][c], 0, 0, 0);
        }
    }
    #pragma unroll
    for (int r = 0; r < 4; ++r) {
        #pragma unroll
        for (int c = 0; c < 8; ++c) {
            const int col = wc + c * 16 + lr;
            #pragma unroll
            for (int i = 0; i < 4; ++i) {
                const int row = q0 + r * 16 + (lane >> 4) * 4 + i;
                AV[((size_t)(b * S_ + row)) * HD_ + h * D_ + col] = f2bf(acc[r][c][i]);
            }
        }
    }
}

// ---------------------------------------------------------------------------
// K6: Y = AV(bf16) @ Wobf^T + bo + value. No LDS. grid (128, 2), block 256
// (4 waves; wave w owns cols w*64..+63 within the 256-col slab).
// ---------------------------------------------------------------------------
__global__ __launch_bounds__(256) void out_frag(
    const unsigned short* __restrict__ AV, const unsigned short* __restrict__ Wobf,
    const float* __restrict__ bo, const float* __restrict__ Vres,
    float* __restrict__ Y)
{
    const int m0 = blockIdx.x * 64;
    const int n0 = blockIdx.y * 256;

    const int t = threadIdx.x;
    const int wave = t >> 6, lane = t & 63;
    const int wc = wave * 64;
    const int lr = lane & 15;
    const int lk = (lane >> 4) * 8;

    f32x4 acc[4][4];
    #pragma unroll
    for (int r = 0; r < 4; ++r)
        #pragma unroll
        for (int c = 0; c < 4; ++c) acc[r][c] = (f32x4){0.f, 0.f, 0.f, 0.f};

    for (int k0 = 0; k0 < HD_; k0 += 32) {
        bf16x8 af[4];
        #pragma unroll
        for (int r = 0; r < 4; ++r)
            af[r] = *(const bf16x8*)&AV[(size_t)(m0 + r * 16 + lr) * HD_ + k0 + lk];
        #pragma unroll
        for (int c = 0; c < 4; ++c) {
            bf16x8 bf = *(const bf16x8*)&Wobf[(size_t)(n0 + wc + c * 16 + lr) * HD_ + k0 + lk];
            #pragma unroll
            for (int r = 0; r < 4; ++r)
                acc[r][c] = __builtin_amdgcn_mfma_f32_16x16x32_bf16(af[r], bf, acc[r][c], 0, 0, 0);
        }
    }
    #pragma unroll
    for (int r = 0; r < 4; ++r) {
        #pragma unroll
        for (int c = 0; c < 4; ++c) {
            const int n = n0 + wc + c * 16 + lr;
            #pragma unroll
            for (int i = 0; i < 4; ++i) {
                const int m = m0 + r * 16 + (lane >> 4) * 4 + i;
                const size_t o = (size_t)m * D_ + n;
                Y[o] = acc[r][c][i] + bo[n] + Vres[o];
            }
        }
    }
}

// ---------------------------------------------------------------------------
// K7: LayerNorm in place. grid 2048, block 256.
// ---------------------------------------------------------------------------
__global__ __launch_bounds__(256) void ln_kernel(
    float* __restrict__ Y, const float* __restrict__ gamma,
    const float* __restrict__ beta)
{
    const int lane = threadIdx.x & 63;
    const int wave = threadIdx.x >> 6;
    const size_t row = (size_t)blockIdx.x * 4 + wave;
    float* p = Y + row * D_;
    float4 v0 = *(float4*)&p[lane * 4];
    float4 v1 = *(float4*)&p[256 + lane * 4];
    float s = v0.x + v0.y + v0.z + v0.w + v1.x + v1.y + v1.z + v1.w;
    float q = v0.x * v0.x + v0.y * v0.y + v0.z * v0.z + v0.w * v0.w +
              v1.x * v1.x + v1.y * v1.y + v1.z * v1.z + v1.w * v1.w;
    #pragma unroll
    for (int m = 1; m < 64; m <<= 1) {
        s += __shfl_xor(s, m);
        q += __shfl_xor(q, m);
    }
    const float mu  = s * (1.f / 512.f);
    const float var = q * (1.f / 512.f) - mu * mu;
    const float r = rsqrtf(var + 1e-5f);
    const float4 g0 = *(const float4*)&gamma[lane * 4];
    const float4 g1 = *(const float4*)&gamma[256 + lane * 4];
    const float4 b0 = *(const float4*)&beta[lane * 4];
    const float4 b1 = *(const float4*)&beta[256 + lane * 4];
    v0.x = (v0.x - mu) * r * g0.x + b0.x;
    v0.y = (v0.y - mu) * r * g0.y + b0.y;
    v0.z = (v0.z - mu) * r * g0.z + b0.z;
    v0.w = (v0.w - mu) * r * g0.w + b0.w;
    v1.x = (v1.x - mu) * r * g1.x + b1.x;
    v1.y = (v1.y - mu) * r * g1.y + b1.y;
    v1.z = (v1.z - mu) * r * g1.z + b1.z;
    v1.w = (v1.w - mu) * r * g1.w + b1.w;
    *(float4*)&p[lane * 4] = v0;
    *(float4*)&p[256 + lane * 4] = v1;
}

// ---------------------------------------------------------------------------
extern "C" void kernel_launch(void* const* d_in, const int* in_sizes, int n_in,
                              void* d_out, int out_size, void* d_ws, size_t ws_size,
                              hipStream_t stream)
{
    const float* query = (const float*)d_in[0];
    const float* key   = (const float*)d_in[1];
    const float* value = (const float*)d_in[2];
    const float* Wq    = (const float*)d_in[3];
    const float* bq    = (const float*)d_in[4];
    const float* Wk    = (const float*)d_in[5];
    const float* bk    = (const float*)d_in[6];
    const float* Wo    = (const float*)d_in[7];
    const float* bo    = (const float*)d_in[8];
    const float* gamma = (const float*)d_in[9];
    const float* beta  = (const float*)d_in[10];

    float* out  = (float*)d_out;                       // [B,S,D]
    float* attn = out + (size_t)B_ * S_ * D_;          // [B,H,S,S]

    char* ws = (char*)d_ws;
    // Layout (76 MB):
    //   [0,64)   AV bf16 [8192][4096]   (written after Qbf/Kbf are dead)
    //   [0,8)    Qbf bf16 [B][H][S][64] (dead after qk_softmax)
    //   [8,16)   Kbf bf16 [B][H][S][64] (dead after qk_softmax)
    //   [64,72)  Vt  bf16 [8][512][1024]
    //   [72,76)  Wobf bf16 [512][4096]
    unsigned short* AV   = (unsigned short*)ws;
    unsigned short* Qbf  = (unsigned short*)ws;
    unsigned short* Kbf  = (unsigned short*)(ws + ((size_t)8 << 20));
    unsigned short* Vt   = (unsigned short*)(ws + ((size_t)64 << 20));
    unsigned short* Wobf = (unsigned short*)(ws + ((size_t)72 << 20));

    vt_kernel<<<dim3(32, 16, 8), 256, 0, stream>>>(value, Vt);
    wobf_kernel<<<dim3(2048), 256, 0, stream>>>(Wo, Wobf);
    proj_kernel<<<dim3(128, 8), 256, 0, stream>>>(query, Wq, bq, Qbf);
    proj_kernel<<<dim3(128, 8), 256, 0, stream>>>(key,   Wk, bk, Kbf);
    qk_softmax<<<dim3(16, 64), 512, 0, stream>>>(Qbf, Kbf, attn);
    av_frag<<<dim3(16, 64), 256, 0, stream>>>(attn, Vt, AV);
    out_frag<<<dim3(128, 2), 256, 0, stream>>>(AV, Wobf, bo, value, out);
    ln_kernel<<<dim3(2048), 256, 0, stream>>>(out, gamma, beta);
}

// Round 5
// 507.175 us; speedup vs baseline: 3.4858x; 1.2676x over previous
//
#include <hip/hip_runtime.h>
#include <hip/hip_bf16.h>

#define B_ 8
#define S_ 1024
#define D_ 512
#define H_ 8
#define DK_ 64
#define HD_ 4096   // H_*D_

typedef __attribute__((ext_vector_type(8))) short bf16x8;
typedef __attribute__((ext_vector_type(4))) float f32x4;

static __device__ __forceinline__ float bf2f(unsigned short u) {
    unsigned v = ((unsigned)u) << 16;
    return __uint_as_float(v);
}
static __device__ __forceinline__ unsigned short f2bf(float f) {
    unsigned u = __float_as_uint(f);
    unsigned r = (u + 0x7fffu + ((u >> 16) & 1u)) >> 16;  // RNE
    return (unsigned short)r;
}

// P_lds index: [ql][k] with 16B-slot XOR swizzle (slot ^= ql&7). Units: shorts.
static __device__ __forceinline__ int plidx(int ql, int k) {
    return ql * 1024 + ((((k >> 3) ^ (ql & 7))) << 3) + (k & 7);
}

// ---------------------------------------------------------------------------
// K1: P = (X @ W^T + bias) * scale, bf16 out at [B][H][S][dk]. grid (128,8).
// ---------------------------------------------------------------------------
__global__ __launch_bounds__(256) void proj_kernel(
    const float* __restrict__ X, const float* __restrict__ W,
    const float* __restrict__ bias, unsigned short* __restrict__ P, float scale)
{
    const int K = D_;
    __shared__ float As[16][68];
    __shared__ float Bs[16][68];
    const int t  = threadIdx.x;
    const int m0 = blockIdx.x * 64;
    const int n0 = blockIdx.y * 64;
    const int lr = t >> 2;
    const int lc = (t & 3) << 2;
    const int ty = t >> 4;
    const int tx = t & 15;
    float acc[4][4] = {};
    for (int k0 = 0; k0 < K; k0 += 16) {
        float4 a4 = *(const float4*)&X[(size_t)(m0 + lr) * K + k0 + lc];
        As[lc + 0][lr] = a4.x; As[lc + 1][lr] = a4.y;
        As[lc + 2][lr] = a4.z; As[lc + 3][lr] = a4.w;
        float4 b4 = *(const float4*)&W[(size_t)(n0 + lr) * K + k0 + lc];
        Bs[lc + 0][lr] = b4.x; Bs[lc + 1][lr] = b4.y;
        Bs[lc + 2][lr] = b4.z; Bs[lc + 3][lr] = b4.w;
        __syncthreads();
        #pragma unroll
        for (int kk = 0; kk < 16; ++kk) {
            float4 av = *(const float4*)&As[kk][ty * 4];
            float4 bv = *(const float4*)&Bs[kk][tx * 4];
            float a[4] = {av.x, av.y, av.z, av.w};
            float b[4] = {bv.x, bv.y, bv.z, bv.w};
            #pragma unroll
            for (int i = 0; i < 4; ++i)
                #pragma unroll
                for (int j = 0; j < 4; ++j) acc[i][j] += a[i] * b[j];
        }
        __syncthreads();
    }
    const int b = m0 >> 10;           // 64-row tile never crosses b
    #pragma unroll
    for (int i = 0; i < 4; ++i) {
        int m = m0 + ty * 4 + i;
        int s = m & 1023;
        #pragma unroll
        for (int j = 0; j < 4; ++j) {
            int n = n0 + tx * 4 + j;
            int h = n >> 6, dk = n & 63;
            P[((((size_t)b * H_ + h) * S_) + s) * DK_ + dk] = f2bf((acc[i][j] + bias[n]) * scale);
        }
    }
}

// ---------------------------------------------------------------------------
// K2: V transpose+convert: Vt[b][e][s] bf16 from V[b][s][e] f32.
// ---------------------------------------------------------------------------
__global__ __launch_bounds__(256) void vt_kernel(
    const float* __restrict__ V, unsigned short* __restrict__ Vt)
{
    __shared__ float tile[32][33];
    const int b = blockIdx.z, s0 = blockIdx.x * 32, e0 = blockIdx.y * 32;
    const int t = threadIdx.x;
    const int r = t >> 3, c4 = (t & 7) * 4;
    float4 v = *(const float4*)&V[((size_t)b * S_ + s0 + r) * D_ + e0 + c4];
    tile[r][c4 + 0] = v.x; tile[r][c4 + 1] = v.y;
    tile[r][c4 + 2] = v.z; tile[r][c4 + 3] = v.w;
    __syncthreads();
    ushort4 u;
    u.x = f2bf(tile[c4 + 0][r]); u.y = f2bf(tile[c4 + 1][r]);
    u.z = f2bf(tile[c4 + 2][r]); u.w = f2bf(tile[c4 + 3][r]);
    *(ushort4*)&Vt[((size_t)b * D_ + e0 + r) * S_ + s0 + c4] = u;
}

// ---------------------------------------------------------------------------
// K3: Wo f32 -> bf16.
// ---------------------------------------------------------------------------
__global__ __launch_bounds__(256) void wobf_kernel(
    const float* __restrict__ Wo, unsigned short* __restrict__ Wobf)
{
    const size_t i = ((size_t)blockIdx.x * 256 + threadIdx.x) * 4;
    float4 v = *(const float4*)&Wo[i];
    ushort4 u = { f2bf(v.x), f2bf(v.y), f2bf(v.z), f2bf(v.w) };
    *(ushort4*)&Wobf[i] = u;
}

// ---------------------------------------------------------------------------
// K4: FUSED attention: swapped QK^T -> softmax -> attn f32 write (once)
//     -> P bf16 into swizzled LDS -> PV MFMA -> AV bf16.
// One block per (b,h,64-q). 8 waves; wave w owns k-cols [w*128,+128) in QK
// and e-cols [w*64,+64) in PV. grid (16, 64), block 512.
// ---------------------------------------------------------------------------
__global__ __launch_bounds__(512, 2) void fused_attn(
    const unsigned short* __restrict__ Qbf,   // [B][H][S][64], pre-scaled 0.125
    const unsigned short* __restrict__ Kbf,   // [B][H][S][64]
    const unsigned short* __restrict__ Vt,    // [B][512][1024]
    float* __restrict__ attn,                 // [B][H][S][S]
    unsigned short* __restrict__ AV)          // [B*S][4096]
{
    const int bh = blockIdx.y;
    const int b = bh >> 3, h = bh & 7;
    const int q0 = blockIdx.x * 64;
    const unsigned short* Qb = Qbf + (size_t)bh * S_ * DK_;
    const unsigned short* Kb = Kbf + (size_t)bh * S_ * DK_;
    const unsigned short* Vb = Vt + (size_t)b * D_ * S_;
    float* outp = attn + ((size_t)bh << 20);

    __shared__ unsigned short PL[64 * 1024];   // 128 KB, swizzled [q][k] bf16
    __shared__ float redm[64][8];
    __shared__ float rowm[64];

    const int t = threadIdx.x;
    const int wave = t >> 6, lane = t & 63;
    const int wcol = wave * 128;    // QK: this wave's k-col window
    const int lr = lane & 15;
    const int g  = lane >> 4;       // 0..3

    // ---- QK^T (swapped): acc[r][c][i] = S[k = wcol+r*16+g*4+i][q = c*16+lr]
    f32x4 acc[8][4];
    #pragma unroll
    for (int r = 0; r < 8; ++r)
        #pragma unroll
        for (int c = 0; c < 4; ++c) acc[r][c] = (f32x4){0.f, 0.f, 0.f, 0.f};

    #pragma unroll
    for (int kk = 0; kk < 2; ++kk) {
        bf16x8 af[8];   // K fragments (A operand, rows = k-cols)
        #pragma unroll
        for (int r = 0; r < 8; ++r)
            af[r] = *(const bf16x8*)&Kb[(size_t)(wcol + r * 16 + lr) * DK_ + kk * 32 + g * 8];
        bf16x8 qf[4];   // Q fragments (B operand, cols = q-rows)
        #pragma unroll
        for (int c = 0; c < 4; ++c)
            qf[c] = *(const bf16x8*)&Qb[(size_t)(q0 + c * 16 + lr) * DK_ + kk * 32 + g * 8];
        #pragma unroll
        for (int r = 0; r < 8; ++r)
            #pragma unroll
            for (int c = 0; c < 4; ++c)
                acc[r][c] = __builtin_amdgcn_mfma_f32_16x16x32_bf16(af[r], qf[c], acc[r][c], 0, 0, 0);
    }

    // ---- softmax: wave-local max over k (regs + g-shfl), cross-wave via LDS
    float mloc[4];
    #pragma unroll
    for (int c = 0; c < 4; ++c) {
        float m = acc[0][c][0];
        #pragma unroll
        for (int r = 0; r < 8; ++r)
            #pragma unroll
            for (int i = 0; i < 4; ++i) m = fmaxf(m, acc[r][c][i]);
        m = fmaxf(m, __shfl_xor(m, 16));
        m = fmaxf(m, __shfl_xor(m, 32));
        mloc[c] = m;
    }
    if (lane < 16) {
        #pragma unroll
        for (int c = 0; c < 4; ++c) redm[c * 16 + lane][wave] = mloc[c];
    }
    __syncthreads();
    if (t < 64) {
        float m = redm[t][0];
        #pragma unroll
        for (int w = 1; w < 8; ++w) m = fmaxf(m, redm[t][w]);
        rowm[t] = m;
    }
    __syncthreads();
    float sloc[4];
    #pragma unroll
    for (int c = 0; c < 4; ++c) {
        const float m = rowm[c * 16 + lr];
        float s = 0.f;
        #pragma unroll
        for (int r = 0; r < 8; ++r)
            #pragma unroll
            for (int i = 0; i < 4; ++i) {
                float p = __expf(acc[r][c][i] - m);
                acc[r][c][i] = p;
                s += p;
            }
        s += __shfl_xor(s, 16);
        s += __shfl_xor(s, 32);
        sloc[c] = s;
    }
    __syncthreads();   // redm reuse hazard
    if (lane < 16) {
        #pragma unroll
        for (int c = 0; c < 4; ++c) redm[c * 16 + lane][wave] = sloc[c];
    }
    __syncthreads();
    if (t < 64) {
        float s = redm[t][0];
        #pragma unroll
        for (int w = 1; w < 8; ++w) s += redm[t][w];
        rowm[t] = 1.0f / s;
    }
    __syncthreads();

    // ---- normalize; write attn f32 (float4) and P bf16 -> swizzled LDS
    #pragma unroll
    for (int c = 0; c < 4; ++c) {
        const int ql = c * 16 + lr;
        const float ri = rowm[ql];
        const size_t rowoff = (size_t)(q0 + ql) << 10;
        #pragma unroll
        for (int r = 0; r < 8; ++r) {
            f32x4 v = acc[r][c];
            v[0] *= ri; v[1] *= ri; v[2] *= ri; v[3] *= ri;
            const int k = wcol + r * 16 + g * 4;
            *(f32x4*)&outp[rowoff + k] = v;
            unsigned p01 = (unsigned)f2bf(v[0]) | ((unsigned)f2bf(v[1]) << 16);
            unsigned p23 = (unsigned)f2bf(v[2]) | ((unsigned)f2bf(v[3]) << 16);
            uint2 pk = { p01, p23 };
            *(uint2*)&PL[plidx(ql, k)] = pk;
        }
    }
    __syncthreads();

    // ---- PV: O[q][e] = sum_k P[q][k] V[k][e]; wave owns e in [wave*64,+64)
    const int we = wave * 64;
    f32x4 accv[4][4];
    #pragma unroll
    for (int r = 0; r < 4; ++r)
        #pragma unroll
        for (int c = 0; c < 4; ++c) accv[r][c] = (f32x4){0.f, 0.f, 0.f, 0.f};

    for (int k0 = 0; k0 < S_; k0 += 32) {
        bf16x8 pa[4];
        #pragma unroll
        for (int r = 0; r < 4; ++r) {
            const int ql = r * 16 + lr;
            pa[r] = *(const bf16x8*)&PL[plidx(ql, k0 + g * 8)];
        }
        #pragma unroll
        for (int c = 0; c < 4; ++c) {
            const int e = we + c * 16 + lr;
            bf16x8 vf = *(const bf16x8*)&Vb[(size_t)e * S_ + k0 + g * 8];
            #pragma unroll
            for (int r = 0; r < 4; ++r)
                accv[r][c] = __builtin_amdgcn_mfma_f32_16x16x32_bf16(pa[r], vf, accv[r][c], 0, 0, 0);
        }
    }
    #pragma unroll
    for (int r = 0; r < 4; ++r) {
        #pragma unroll
        for (int c = 0; c < 4; ++c) {
            const int e = we + c * 16 + lr;
            #pragma unroll
            for (int i = 0; i < 4; ++i) {
                const int row = q0 + r * 16 + g * 4 + i;
                AV[((size_t)(b * S_ + row)) * HD_ + h * D_ + e] = f2bf(accv[r][c][i]);
            }
        }
    }
}

// ---------------------------------------------------------------------------
// K5: Y = AV(bf16) @ Wobf^T + bo + value. grid (128, 2), block 256.
// ---------------------------------------------------------------------------
__global__ __launch_bounds__(256) void out_frag(
    const unsigned short* __restrict__ AV, const unsigned short* __restrict__ Wobf,
    const float* __restrict__ bo, const float* __restrict__ Vres,
    float* __restrict__ Y)
{
    const int m0 = blockIdx.x * 64;
    const int n0 = blockIdx.y * 256;

    const int t = threadIdx.x;
    const int wave = t >> 6, lane = t & 63;
    const int wc = wave * 64;
    const int lr = lane & 15;
    const int lk = (lane >> 4) * 8;

    f32x4 acc[4][4];
    #pragma unroll
    for (int r = 0; r < 4; ++r)
        #pragma unroll
        for (int c = 0; c < 4; ++c) acc[r][c] = (f32x4){0.f, 0.f, 0.f, 0.f};

    for (int k0 = 0; k0 < HD_; k0 += 32) {
        bf16x8 af[4];
        #pragma unroll
        for (int r = 0; r < 4; ++r)
            af[r] = *(const bf16x8*)&AV[(size_t)(m0 + r * 16 + lr) * HD_ + k0 + lk];
        #pragma unroll
        for (int c = 0; c < 4; ++c) {
            bf16x8 bf = *(const bf16x8*)&Wobf[(size_t)(n0 + wc + c * 16 + lr) * HD_ + k0 + lk];
            #pragma unroll
            for (int r = 0; r < 4; ++r)
                acc[r][c] = __builtin_amdgcn_mfma_f32_16x16x32_bf16(af[r], bf, acc[r][c], 0, 0, 0);
        }
    }
    #pragma unroll
    for (int r = 0; r < 4; ++r) {
        #pragma unroll
        for (int c = 0; c < 4; ++c) {
            const int n = n0 + wc + c * 16 + lr;
            #pragma unroll
            for (int i = 0; i < 4; ++i) {
                const int m = m0 + r * 16 + (lane >> 4) * 4 + i;
                const size_t o = (size_t)m * D_ + n;
                Y[o] = acc[r][c][i] + bo[n] + Vres[o];
            }
        }
    }
}

// ---------------------------------------------------------------------------
// K6: LayerNorm in place. grid 2048, block 256.
// ---------------------------------------------------------------------------
__global__ __launch_bounds__(256) void ln_kernel(
    float* __restrict__ Y, const float* __restrict__ gamma,
    const float* __restrict__ beta)
{
    const int lane = threadIdx.x & 63;
    const int wave = threadIdx.x >> 6;
    const size_t row = (size_t)blockIdx.x * 4 + wave;
    float* p = Y + row * D_;
    float4 v0 = *(float4*)&p[lane * 4];
    float4 v1 = *(float4*)&p[256 + lane * 4];
    float s = v0.x + v0.y + v0.z + v0.w + v1.x + v1.y + v1.z + v1.w;
    float q = v0.x * v0.x + v0.y * v0.y + v0.z * v0.z + v0.w * v0.w +
              v1.x * v1.x + v1.y * v1.y + v1.z * v1.z + v1.w * v1.w;
    #pragma unroll
    for (int m = 1; m < 64; m <<= 1) {
        s += __shfl_xor(s, m);
        q += __shfl_xor(q, m);
    }
    const float mu  = s * (1.f / 512.f);
    const float var = q * (1.f / 512.f) - mu * mu;
    const float r = rsqrtf(var + 1e-5f);
    const float4 g0 = *(const float4*)&gamma[lane * 4];
    const float4 g1 = *(const float4*)&gamma[256 + lane * 4];
    const float4 b0 = *(const float4*)&beta[lane * 4];
    const float4 b1 = *(const float4*)&beta[256 + lane * 4];
    v0.x = (v0.x - mu) * r * g0.x + b0.x;
    v0.y = (v0.y - mu) * r * g0.y + b0.y;
    v0.z = (v0.z - mu) * r * g0.z + b0.z;
    v0.w = (v0.w - mu) * r * g0.w + b0.w;
    v1.x = (v1.x - mu) * r * g1.x + b1.x;
    v1.y = (v1.y - mu) * r * g1.y + b1.y;
    v1.z = (v1.z - mu) * r * g1.z + b1.z;
    v1.w = (v1.w - mu) * r * g1.w + b1.w;
    *(float4*)&p[lane * 4] = v0;
    *(float4*)&p[256 + lane * 4] = v1;
}

// ---------------------------------------------------------------------------
extern "C" void kernel_launch(void* const* d_in, const int* in_sizes, int n_in,
                              void* d_out, int out_size, void* d_ws, size_t ws_size,
                              hipStream_t stream)
{
    const float* query = (const float*)d_in[0];
    const float* key   = (const float*)d_in[1];
    const float* value = (const float*)d_in[2];
    const float* Wq    = (const float*)d_in[3];
    const float* bq    = (const float*)d_in[4];
    const float* Wk    = (const float*)d_in[5];
    const float* bk    = (const float*)d_in[6];
    const float* Wo    = (const float*)d_in[7];
    const float* bo    = (const float*)d_in[8];
    const float* gamma = (const float*)d_in[9];
    const float* beta  = (const float*)d_in[10];

    float* out  = (float*)d_out;                       // [B,S,D] (16 MiB)
    float* attn = out + (size_t)B_ * S_ * D_;          // [B,H,S,S] (256 MiB)

    char* ws = (char*)d_ws;
    // ws (76 MB): AV [0,64) bf16 ; Vt [64,72) bf16 ; Wobf [72,76) bf16.
    unsigned short* AV   = (unsigned short*)ws;
    unsigned short* Vt   = (unsigned short*)(ws + ((size_t)64 << 20));
    unsigned short* Wobf = (unsigned short*)(ws + ((size_t)72 << 20));
    // Qbf/Kbf (8 MiB each = exactly the 16 MiB OUT region of d_out);
    // dead before out_frag overwrites that region (stream-ordered).
    // NOTE: offsets are in SHORTS — Kbf at 4M shorts = byte offset 8 MiB.
    unsigned short* Qbf  = (unsigned short*)d_out;
    unsigned short* Kbf  = (unsigned short*)d_out + ((size_t)4 << 20);

    vt_kernel<<<dim3(32, 16, 8), 256, 0, stream>>>(value, Vt);
    wobf_kernel<<<dim3(2048), 256, 0, stream>>>(Wo, Wobf);
    proj_kernel<<<dim3(128, 8), 256, 0, stream>>>(query, Wq, bq, Qbf, 0.125f);
    proj_kernel<<<dim3(128, 8), 256, 0, stream>>>(key,   Wk, bk, Kbf, 1.0f);
    fused_attn<<<dim3(16, 64), 512, 0, stream>>>(Qbf, Kbf, Vt, attn, AV);
    out_frag<<<dim3(128, 2), 256, 0, stream>>>(AV, Wobf, bo, value, out);
    ln_kernel<<<dim3(2048), 256, 0, stream>>>(out, gamma, beta);
}